// Round 6
// baseline (143.666 us; speedup 1.0000x reference)
//
#include <hip/hip_runtime.h>

#define W 512

__device__ __forceinline__ float fexp2(float x) {
#if __has_builtin(__builtin_amdgcn_exp2f)
    return __builtin_amdgcn_exp2f(x);
#else
    return __expf(x * 0.6931471805599453f);
#endif
}

// ---------------- tiny min/max pre-pass: 256 contention-free partials ----------------
__global__ __launch_bounds__(256) void k_minmax(const float* __restrict__ y,
                                                float2* __restrict__ partial) {
    __shared__ float smn[256], smx[256];
    int t = threadIdx.x;
    const float4* y4 = (const float4*)y;
    float4 v = y4[blockIdx.x * 256 + t];
    float mn = fminf(fminf(v.x, v.y), fminf(v.z, v.w));
    float mx = fmaxf(fmaxf(v.x, v.y), fmaxf(v.z, v.w));
    smn[t] = mn; smx[t] = mx;
    __syncthreads();
    for (int off = 128; off > 0; off >>= 1) {
        if (t < off) {
            smn[t] = fminf(smn[t], smn[t + off]);
            smx[t] = fmaxf(smx[t], smx[t + off]);
        }
        __syncthreads();
    }
    if (t == 0) partial[blockIdx.x] = make_float2(smn[0], smx[0]);
}

// ---------------- box kernel: produce (Xb,yb) and (Xd,Dd) for every pixel --------
// Block (0,0) additionally reduces the 256 min/max partials -> k2 scalar.
__global__ __launch_bounds__(256) void k_box(const float* __restrict__ X,
                                             const float* __restrict__ y,
                                             const float2* __restrict__ partial,
                                             const float* __restrict__ r,
                                             float2* __restrict__ bXY_g,
                                             float2* __restrict__ dXD_g,
                                             float* __restrict__ k2out) {
    __shared__ __align__(16) float lds[1920];
    float* sX  = lds;          // 24*24
    float* sY  = sX + 576;     // 24*24
    float* csX = sY + 576;     // 16*24
    float* csY = csX + 384;    // 16*24

    int tx = threadIdx.x, ty = threadIdx.y;
    int t = ty * 16 + tx;
    int c0 = blockIdx.x * 16, r0 = blockIdx.y * 16;

    if (blockIdx.x == 0 && blockIdx.y == 0) {
        float2* red = (float2*)lds;             // alias, dead before staging
        red[t] = partial[t];
        __syncthreads();
        for (int off = 128; off > 0; off >>= 1) {
            if (t < off) {
                red[t].x = fminf(red[t].x, red[t + off].x);
                red[t].y = fmaxf(red[t].y, red[t + off].y);
            }
            __syncthreads();
        }
        if (t == 0) {
            float sigma = r[0] * (red[0].y - red[0].x);
            float hh = 0.5f * sigma;
            k2out[0] = -1.4426950408889634f / (hh * hh);
        }
        __syncthreads();
    }

    // stage 24x24 X,y with halo 4 (zero outside image)
    for (int i = t; i < 576; i += 256) {
        int rr = i / 24, cc = i - rr * 24;
        int gr = r0 - 4 + rr, gc = c0 - 4 + cc;
        bool ok = ((unsigned)gr < 512u) & ((unsigned)gc < 512u);
        float xv = 0.f, yv = 0.f;
        if (ok) { xv = X[gr * W + gc]; yv = y[gr * W + gc]; }
        sX[i] = xv; sY[i] = yv;
    }
    __syncthreads();

    // 9-row column sums
    for (int i = t; i < 384; i += 256) {
        int rr = i / 24, cc = i - rr * 24;
        float ax = 0.f, ay = 0.f;
#pragma unroll
        for (int k = 0; k < 9; ++k) { ax += sX[(rr + k) * 24 + cc]; ay += sY[(rr + k) * 24 + cc]; }
        csX[i] = ax; csY[i] = ay;
    }
    __syncthreads();

    // 9-col sums -> per-pixel base + detail, write to global
    const float inv81 = 1.0f / 81.0f;
    float ax = 0.f, ay = 0.f;
#pragma unroll
    for (int k = 0; k < 9; ++k) { ax += csX[ty * 24 + tx + k]; ay += csY[ty * 24 + tx + k]; }
    float Xb = ax * inv81, yb = ay * inv81;
    float xc = sX[(ty + 4) * 24 + tx + 4];
    float yc = sY[(ty + 4) * 24 + tx + 4];
    float xd = xc - Xb;
    int p = (r0 + ty) * W + (c0 + tx);
    bXY_g[p] = make_float2(Xb, yb);
    dXD_g[p] = make_float2(xd, (yc - yb) - xd);
}

// ---------------- bilateral kernel: 4 vertical px/thread, max-ILP single wave/SIMD ----
// Tile 64 cols x 8 rows, block (64,2): thread (tx,ty) owns col c0+tx, rows h0..h0+3
// with h0 = r0 + 4*ty. Each LDS row-read and each column mask feeds 4 centers.
// Vertical spatial weights via zero-padded tables (branchless row masking).
__global__ __launch_bounds__(128, 1) void k_bil(const float2* __restrict__ bXY_g,
                                                const float2* __restrict__ dXD_g,
                                                const float* __restrict__ k2buf,
                                                float* __restrict__ out) {
    __shared__ float sbe[25];   // dy = i-12, zero outside |dy|<=9
    __shared__ float sde[11];   // dy = i-5,  zero outside |dy|<=2
    __shared__ __align__(16) float2 bXYs[26 * 82];  // rows r0-9..r0+16, cols c0-9..c0+72
    __shared__ __align__(16) float2 dXDs[12 * 72];  // rows r0-2..r0+9,  cols c0-4..c0+67

    int tx = threadIdx.x;            // 0..63
    int ty = threadIdx.y;            // 0..1
    int t = ty * 64 + tx;
    int c0 = blockIdx.x * 64, r0 = blockIdx.y * 8;

    if (t < 25)                 { int dy = t - 12; sbe[t] = (dy * dy <= 81) ? __expf(-(float)(dy * dy) / 8145.0625f) : 0.f; }
    else if (t >= 32 && t < 43) { int i = t - 32; int dy = i - 5; sde[i] = (dy * dy <= 4) ? __expf(-(float)(dy * dy) / 126.5625f) : 0.f; }

    float k2 = k2buf[0];

    // ---- stage precomputed tiles (zero outside image) ----
    for (int i = t; i < 26 * 82; i += 128) {
        int rr = i / 82, cc2 = i - rr * 82;
        int gr = r0 - 9 + rr, gc = c0 - 9 + cc2;
        float2 v = make_float2(0.f, 0.f);
        if (((unsigned)gr < 512u) & ((unsigned)gc < 512u)) v = bXY_g[gr * W + gc];
        bXYs[i] = v;
    }
    for (int i = t; i < 12 * 72; i += 128) {
        int rr = i / 72, cc2 = i - rr * 72;
        int gr = r0 - 2 + rr, gc = c0 - 4 + cc2;
        float2 v = make_float2(0.f, 0.f);
        if (((unsigned)gr < 512u) & ((unsigned)gc < 512u)) v = dXD_g[gr * W + gc];
        dXDs[i] = v;
    }
    __syncthreads();

    int c = c0 + tx;
    int h0 = r0 + 4 * ty;

    // chunk mapping: output col -> owning chunk after overlap-trim (column-only, shared by 4 px)
    int chunk = (c == 0) ? 0 : (c - 1) / 62;
    if (chunk > 8) chunk = 8;
    int s = 62 * chunk;
    int e = (chunk == 8) ? 512 : (s + 64);

    const float ksb = -1.4426950408889634f / 8145.0625f;
    const float ksd = -1.4426950408889634f / 126.5625f;
    float cc[19];
#pragma unroll
    for (int j = 0; j < 19; ++j) {
        int nc = c - 9 + j, d = j - 9;
        cc[j] = ((nc >= s) & (nc < e)) ? ksb * (float)(d * d) : -1e30f;
    }
    float ccd[9];
#pragma unroll
    for (int j = 0; j < 9; ++j) {
        int nc = c - 4 + j, d = j - 4;
        ccd[j] = ((nc >= s) & (nc < e)) ? ksd * (float)(d * d) : -1e30f;
    }

    float Xc[4], Xd[4];
#pragma unroll
    for (int p = 0; p < 4; ++p) {
        Xc[p] = bXYs[(4 * ty + 9 + p) * 82 + tx + 9].x;
        Xd[p] = dXDs[(4 * ty + 2 + p) * 72 + tx + 4].x;
    }

    float s_w[4], s_wx[4], s_wy[4], s_wxx[4], s_wxy[4];
#pragma unroll
    for (int p = 0; p < 4; ++p) { s_w[p] = 0.f; s_wx[p] = 0.f; s_wy[p] = 0.f; s_wxx[p] = 0.f; s_wxy[p] = 0.f; }

    // ---- base pass: 22 rows cover nh in [h0-9, h0+12]; each row feeds 4 centers ----
#pragma unroll 1
    for (int k = 0; k < 22; ++k) {
        int nh = h0 - 9 + k;
        bool valid = (unsigned)nh < 512u;          // wave-uniform
        const float2* xr = bXYs + (4 * ty + k) * 82 + tx;
        float vx[19], vy[19];
#pragma unroll
        for (int j = 0; j < 19; ++j) { float2 v = xr[j]; vx[j] = v.x; vy[j] = v.y; }
        float rs[4], rsx[4], rsy[4], rsxx[4], rsxy[4];
#pragma unroll
        for (int p = 0; p < 4; ++p) { rs[p] = 0.f; rsx[p] = 0.f; rsy[p] = 0.f; rsxx[p] = 0.f; rsxy[p] = 0.f; }
#pragma unroll
        for (int j = 0; j < 19; ++j) {
#pragma unroll
            for (int p = 0; p < 4; ++p) {
                float u = vx[j] - Xc[p];
                float a = fmaf(u * k2, u, cc[j]);
                float w = fexp2(a);
                rs[p] += w;
                rsx[p] = fmaf(w, vx[j], rsx[p]);
                rsy[p] = fmaf(w, vy[j], rsy[p]);
                float tt = w * vx[j];
                rsxx[p] = fmaf(tt, vx[j], rsxx[p]);
                rsxy[p] = fmaf(tt, vy[j], rsxy[p]);
            }
        }
#pragma unroll
        for (int p = 0; p < 4; ++p) {
            float ey = valid ? sbe[k + 3 - p] : 0.f;   // dy = k-9-p; zero-padded table
            s_w[p]   = fmaf(ey, rs[p],   s_w[p]);
            s_wx[p]  = fmaf(ey, rsx[p],  s_wx[p]);
            s_wy[p]  = fmaf(ey, rsy[p],  s_wy[p]);
            s_wxx[p] = fmaf(ey, rsxx[p], s_wxx[p]);
            s_wxy[p] = fmaf(ey, rsxy[p], s_wxy[p]);
        }
    }

    // ---- detail pass: 8 rows cover nh in [h0-2, h0+5] ----
    float s_wd[4], s_v[4];
#pragma unroll
    for (int p = 0; p < 4; ++p) { s_wd[p] = 0.f; s_v[p] = 0.f; }
#pragma unroll 1
    for (int kd = 0; kd < 8; ++kd) {
        int nh = h0 - 2 + kd;
        bool valid = (unsigned)nh < 512u;
        const float2* dr = dXDs + (4 * ty + kd) * 72 + tx;
        float vx[9], vd[9];
#pragma unroll
        for (int j = 0; j < 9; ++j) { float2 v = dr[j]; vx[j] = v.x; vd[j] = v.y; }
        float rs[4], rv[4];
#pragma unroll
        for (int p = 0; p < 4; ++p) { rs[p] = 0.f; rv[p] = 0.f; }
#pragma unroll
        for (int j = 0; j < 9; ++j) {
#pragma unroll
            for (int p = 0; p < 4; ++p) {
                float u = vx[j] - Xd[p];
                float a = fmaf(u * k2, u, ccd[j]);
                float w = fexp2(a);
                rs[p] += w;
                rv[p] = fmaf(w, vd[j], rv[p]);
            }
        }
#pragma unroll
        for (int p = 0; p < 4; ++p) {
            float ey = valid ? sde[kd + 3 - p] : 0.f;  // dy = kd-2-p
            s_wd[p] = fmaf(ey, rs[p], s_wd[p]);
            s_v[p]  = fmaf(ey, rv[p], s_v[p]);
        }
    }

    // ---- combine & store 4 px ----
#pragma unroll
    for (int p = 0; p < 4; ++p) {
        float inv  = 1.0f / s_w[p];
        float mx   = s_wx[p] * inv, my = s_wy[p] * inv;
        float varx = fmaf(-mx, mx, s_wxx[p] * inv);
        float cov  = fmaf(-mx, my, s_wxy[p] * inv);
        float A    = cov / (varx + 1e-6f);
        float b    = my - A * mx;
        float bd   = s_v[p] / s_wd[p];
        out[(h0 + p) * W + c] = fmaf(A, Xc[p], b) + Xd[p] + bd;
    }
}

// ---------------- fallback: R1 fused kernel (used only if workspace too small) ---
__global__ __launch_bounds__(256, 4) void k_fused(const float* __restrict__ X,
                                                  const float* __restrict__ y,
                                                  const float2* __restrict__ partial,
                                                  const float* __restrict__ r,
                                                  float* __restrict__ out) {
    __shared__ float sbx[19];
    __shared__ float sdy[5];
    __shared__ __align__(16) char ldsbuf[38624];
    float*  sX  = (float*)ldsbuf;
    float*  sY  = sX + 42 * 42;
    float*  csX = sY + 42 * 42;
    float*  csY = csX + 34 * 42;
    float2* bXY = (float2*)(csY + 34 * 42);
    float2* dXD = bXY + 34 * 34;
    float2* red = (float2*)sX;

    int tx = threadIdx.x, ty = threadIdx.y;
    int t = ty * 16 + tx;
    int c0 = blockIdx.x * 16, r0 = blockIdx.y * 16;

    if (t < 19)      { int d = t - 9;  sbx[t]      = __expf(-(float)(d * d) / 8145.0625f); }
    else if (t < 24) { int d = t - 21; sdy[t - 19] = __expf(-(float)(d * d) / 126.5625f); }

    red[t] = partial[t];
    __syncthreads();
    for (int off = 128; off > 0; off >>= 1) {
        if (t < off) {
            red[t].x = fminf(red[t].x, red[t + off].x);
            red[t].y = fmaxf(red[t].y, red[t + off].y);
        }
        __syncthreads();
    }
    float2 mm0 = red[0];
    __syncthreads();
    float sigma = r[0] * (mm0.y - mm0.x);
    float hh = 0.5f * sigma;
    float k2 = -1.4426950408889634f / (hh * hh);

    for (int i = t; i < 42 * 42; i += 256) {
        int rr = i / 42, cc2 = i - rr * 42;
        int gr = r0 - 13 + rr, gc = c0 - 13 + cc2;
        bool ok = ((unsigned)gr < 512u) & ((unsigned)gc < 512u);
        float xv = 0.f, yv = 0.f;
        if (ok) { xv = X[gr * W + gc]; yv = y[gr * W + gc]; }
        sX[i] = xv; sY[i] = yv;
    }
    __syncthreads();

    for (int i = t; i < 34 * 42; i += 256) {
        int rr = i / 42, cc2 = i - rr * 42;
        float ax = 0.f, ay = 0.f;
#pragma unroll
        for (int k = 0; k < 9; ++k) { ax += sX[(rr + k) * 42 + cc2]; ay += sY[(rr + k) * 42 + cc2]; }
        csX[i] = ax; csY[i] = ay;
    }
    __syncthreads();

    const float inv81 = 1.0f / 81.0f;
    for (int i = t; i < 34 * 34; i += 256) {
        int rr = i / 34, cc2 = i - rr * 34;
        float ax = 0.f, ay = 0.f;
#pragma unroll
        for (int k = 0; k < 9; ++k) { ax += csX[rr * 42 + cc2 + k]; ay += csY[rr * 42 + cc2 + k]; }
        bXY[i] = make_float2(ax * inv81, ay * inv81);
    }
    __syncthreads();

    for (int i = t; i < 20 * 24; i += 256) {
        int rr = i / 24, cc2 = i - rr * 24;
        float2 b2 = bXY[(rr + 7) * 34 + (cc2 + 5)];
        float xc = sX[(rr + 11) * 42 + (cc2 + 9)];
        float yc = sY[(rr + 11) * 42 + (cc2 + 9)];
        float xd = xc - b2.x;
        dXD[i] = make_float2(xd, (yc - b2.y) - xd);
    }
    __syncthreads();

    int c = c0 + tx;
    int h = r0 + ty;
    int chunk = (c == 0) ? 0 : (c - 1) / 62;
    if (chunk > 8) chunk = 8;
    int s = 62 * chunk;
    int e = (chunk == 8) ? 512 : (s + 64);

    const float ksb = -1.4426950408889634f / 8145.0625f;
    const float ksd = -1.4426950408889634f / 126.5625f;
    float cc[19];
#pragma unroll
    for (int j = 0; j < 19; ++j) {
        int nc = c - 9 + j, d = j - 9;
        cc[j] = ((nc >= s) & (nc < e)) ? ksb * (float)(d * d) : -1e30f;
    }
    float ccd[9];
#pragma unroll
    for (int j = 0; j < 9; ++j) {
        int nc = c - 4 + j, d = j - 4;
        ccd[j] = ((nc >= s) & (nc < e)) ? ksd * (float)(d * d) : -1e30f;
    }

    float Xc = bXY[(ty + 9) * 34 + tx + 9].x;
    float Xd = dXD[(ty + 2) * 24 + tx + 4].x;

    float sw = 0.f, swx = 0.f, swy = 0.f, swxx = 0.f, swxy = 0.f;
#pragma unroll 1
    for (int k = 0; k < 19; ++k) {
        int nh = h - 9 + k;
        if ((unsigned)nh >= 512u) continue;
        const float2* xr = bXY + (ty + k) * 34 + tx;
        float rs = 0.f, rsx = 0.f, rsy = 0.f, rsxx = 0.f, rsxy = 0.f;
#pragma unroll
        for (int j = 0; j < 19; ++j) {
            float2 v = xr[j];
            float u = v.x - Xc;
            float a = fmaf(u * k2, u, cc[j]);
            float w = fexp2(a);
            rs += w;
            rsx = fmaf(w, v.x, rsx);
            rsy = fmaf(w, v.y, rsy);
            float tt = w * v.x;
            rsxx = fmaf(tt, v.x, rsxx);
            rsxy = fmaf(tt, v.y, rsxy);
        }
        float ey = sbx[k];
        sw   = fmaf(ey, rs,   sw);
        swx  = fmaf(ey, rsx,  swx);
        swy  = fmaf(ey, rsy,  swy);
        swxx = fmaf(ey, rsxx, swxx);
        swxy = fmaf(ey, rsxy, swxy);
    }

    float swd = 0.f, sv = 0.f;
#pragma unroll 1
    for (int k = 0; k < 5; ++k) {
        int nh = h - 2 + k;
        if ((unsigned)nh >= 512u) continue;
        const float2* dr2 = dXD + (ty + k) * 24 + tx;
        float rs = 0.f, rv = 0.f;
#pragma unroll
        for (int j = 0; j < 9; ++j) {
            float2 v = dr2[j];
            float u = v.x - Xd;
            float a = fmaf(u * k2, u, ccd[j]);
            float w = fexp2(a);
            rs += w;
            rv = fmaf(w, v.y, rv);
        }
        swd = fmaf(sdy[k], rs, swd);
        sv  = fmaf(sdy[k], rv, sv);
    }

    float inv  = 1.0f / sw;
    float mx   = swx * inv, my = swy * inv;
    float varx = fmaf(-mx, mx, swxx * inv);
    float cov  = fmaf(-mx, my, swxy * inv);
    float A    = cov / (varx + 1e-6f);
    float b    = my - A * mx;
    float bd   = sv / swd;
    out[h * W + c] = fmaf(A, Xc, b) + Xd + bd;
}

extern "C" void kernel_launch(void* const* d_in, const int* in_sizes, int n_in,
                              void* d_out, int out_size, void* d_ws, size_t ws_size,
                              hipStream_t stream) {
    const float* X = (const float*)d_in[0];
    const float* y = (const float*)d_in[1];
    const float* r = (const float*)d_in[2];
    float* out = (float*)d_out;

    float2* partial = (float2*)d_ws;                               // 2048 B
    float*  k2buf   = (float*)((char*)d_ws + 2048);                // 4 B (padded)
    float2* bXY_g   = (float2*)((char*)d_ws + 4096);               // 2 MB
    float2* dXD_g   = (float2*)((char*)d_ws + 4096 + 512 * 512 * 8); // 2 MB
    size_t need = 4096 + (size_t)2 * 512 * 512 * 8;

    k_minmax<<<256, 256, 0, stream>>>(y, partial);
    if (ws_size >= need) {
        k_box<<<dim3(32, 32), dim3(16, 16), 0, stream>>>(X, y, partial, r, bXY_g, dXD_g, k2buf);
        k_bil<<<dim3(8, 64), dim3(64, 2), 0, stream>>>(bXY_g, dXD_g, k2buf, out);
    } else {
        k_fused<<<dim3(32, 32), dim3(16, 16), 0, stream>>>(X, y, partial, r, out);
    }
}

// Round 7
// 92.652 us; speedup vs baseline: 1.5506x; 1.5506x over previous
//
#include <hip/hip_runtime.h>

#define W 512

typedef float v2f __attribute__((ext_vector_type(2)));

__device__ __forceinline__ float fexp2(float x) {
#if __has_builtin(__builtin_amdgcn_exp2f)
    return __builtin_amdgcn_exp2f(x);
#else
    return __expf(x * 0.6931471805599453f);
#endif
}
__device__ __forceinline__ v2f vfma(v2f a, v2f b, v2f c) {
    return __builtin_elementwise_fma(a, b, c);
}
__device__ __forceinline__ v2f bc2(float x) { v2f r; r.x = x; r.y = x; return r; }

// ---------------- tiny min/max pre-pass: 256 contention-free partials ----------------
__global__ __launch_bounds__(256) void k_minmax(const float* __restrict__ y,
                                                float2* __restrict__ partial) {
    __shared__ float smn[256], smx[256];
    int t = threadIdx.x;
    const float4* y4 = (const float4*)y;
    float4 v = y4[blockIdx.x * 256 + t];
    float mn = fminf(fminf(v.x, v.y), fminf(v.z, v.w));
    float mx = fmaxf(fmaxf(v.x, v.y), fmaxf(v.z, v.w));
    smn[t] = mn; smx[t] = mx;
    __syncthreads();
    for (int off = 128; off > 0; off >>= 1) {
        if (t < off) {
            smn[t] = fminf(smn[t], smn[t + off]);
            smx[t] = fmaxf(smx[t], smx[t + off]);
        }
        __syncthreads();
    }
    if (t == 0) partial[blockIdx.x] = make_float2(smn[0], smx[0]);
}

// ---------------- fully fused kernel: box + bilateral, all tiles LDS-resident ----
// Block: 64x4 threads, 2 vertical px/thread -> 64 cols x 8 rows output tile.
// R0-proven structure; base/detail row loops made branchless + unroll 2 so two
// independent row chains interleave (ILP latency hiding at fixed occupancy).
__global__ __launch_bounds__(256) void k_fused(const float* __restrict__ X,
                                               const float* __restrict__ y,
                                               const float2* __restrict__ partial,
                                               const float* __restrict__ r,
                                               float* __restrict__ out) {
    __shared__ float sbx[19];   // row spatial weights, 19x19 filter
    __shared__ float sdy[5];    // row spatial weights, 5x9 filter
    // one LDS arena with phase-based aliasing (60256 B < 64 KB static limit)
    __shared__ __align__(16) char ldsbuf[60256];
    float*  sX  = (float*)ldsbuf;            // 34*90 staged X   (rows r0-13..r0+20, cols c0-13..c0+76)
    float*  sY  = sX + 34 * 90;              // 34*90 staged y
    float*  csX = sY + 34 * 90;              // 26*90 9-row col-sums of X
    float*  csY = csX + 26 * 90;             // 26*90
    float2* bXY = (float2*)(csY + 26 * 90);  // 26*82 (Xb,yb)    (rows r0-9..r0+16, cols c0-9..c0+72)
    float2* dXD = (float2*)csX;              // 12*72 (Xd,Dd) — aliases cs after it's dead
    float2* red = (float2*)sX;               // 256 — prologue alias, dead before staging

    int tx = threadIdx.x, ty = threadIdx.y;
    int t = ty * 64 + tx;
    int c0 = blockIdx.x * 64, r0 = blockIdx.y * 8;

    if (t < 19)      { int d = t - 9;      sbx[t]      = __expf(-(float)(d * d) / 8145.0625f); }
    else if (t < 24) { int d = t - 19 - 2; sdy[t - 19] = __expf(-(float)(d * d) / 126.5625f); }

    // ---- prologue: reduce 256 min/max partials -> k2 ----
    red[t] = partial[t];
    __syncthreads();
    for (int off = 128; off > 0; off >>= 1) {
        if (t < off) {
            red[t].x = fminf(red[t].x, red[t + off].x);
            red[t].y = fmaxf(red[t].y, red[t + off].y);
        }
        __syncthreads();
    }
    float2 mm0 = red[0];
    __syncthreads();                          // red (sX alias) free for staging
    float sigma = r[0] * (mm0.y - mm0.x);
    float hh = 0.5f * sigma;
    float k2 = -1.4426950408889634f / (hh * hh);   // w_range = 2^(u^2*k2)
    v2f k2v = bc2(k2);

    // ---- stage X,y with halo (zero outside image) ----
    for (int i = t; i < 34 * 90; i += 256) {
        int rr = i / 90, cc2 = i - rr * 90;
        int gr = r0 - 13 + rr, gc = c0 - 13 + cc2;
        bool ok = ((unsigned)gr < 512u) & ((unsigned)gc < 512u);
        float xv = 0.f, yv = 0.f;
        if (ok) { xv = X[gr * W + gc]; yv = y[gr * W + gc]; }
        sX[i] = xv; sY[i] = yv;
    }
    __syncthreads();

    // ---- 9-row column sums ----
    for (int i = t; i < 26 * 90; i += 256) {
        int rr = i / 90, cc2 = i - rr * 90;
        float ax = 0.f, ay = 0.f;
#pragma unroll
        for (int k = 0; k < 9; ++k) { ax += sX[(rr + k) * 90 + cc2]; ay += sY[(rr + k) * 90 + cc2]; }
        csX[i] = ax; csY[i] = ay;
    }
    __syncthreads();

    // ---- 9-col sums -> (Xb, yb) tile ----
    const float inv81 = 1.0f / 81.0f;
    for (int i = t; i < 26 * 82; i += 256) {
        int rr = i / 82, cc2 = i - rr * 82;
        float ax = 0.f, ay = 0.f;
#pragma unroll
        for (int k = 0; k < 9; ++k) { ax += csX[rr * 90 + cc2 + k]; ay += csY[rr * 90 + cc2 + k]; }
        bXY[i] = make_float2(ax * inv81, ay * inv81);
    }
    __syncthreads();

    // ---- (Xd, Dd) detail tile (rows r0-2..r0+9, cols c0-4..c0+67); aliases cs ----
    for (int i = t; i < 12 * 72; i += 256) {
        int rr = i / 72, cc2 = i - rr * 72;
        float2 b2 = bXY[(rr + 7) * 82 + (cc2 + 5)];
        float xc = sX[(rr + 11) * 90 + (cc2 + 9)];
        float yc = sY[(rr + 11) * 90 + (cc2 + 9)];
        float xd = xc - b2.x;
        dXD[i] = make_float2(xd, (yc - b2.y) - xd);
    }
    __syncthreads();

    // ---- bilateral passes (all LDS reads) ----
    int c  = blockIdx.x * 64 + tx;
    int h0 = r0 + ty * 2;                      // rows h0, h0+1

    // chunk mapping: output col -> owning chunk after overlap-trim
    int chunk = (c == 0) ? 0 : (c - 1) / 62;
    if (chunk > 8) chunk = 8;
    int s = 62 * chunk;
    int e = (chunk == 8) ? 512 : (s + 64);

    // column exponents (log2-domain spatial) with chunk mask folded in
    const float ksb = -1.4426950408889634f / 8145.0625f;
    const float ksd = -1.4426950408889634f / 126.5625f;
    float cc[19];
#pragma unroll
    for (int j = 0; j < 19; ++j) {
        int nc = c - 9 + j, d = j - 9;
        cc[j] = ((nc >= s) & (nc < e)) ? ksb * (float)(d * d) : -1e30f;
    }
    float ccd[9];
#pragma unroll
    for (int j = 0; j < 9; ++j) {
        int nc = c - 4 + j, d = j - 4;
        ccd[j] = ((nc >= s) & (nc < e)) ? ksd * (float)(d * d) : -1e30f;
    }

    v2f Xc2; Xc2.x = bXY[(2 * ty + 9)  * 82 + tx + 9].x;
             Xc2.y = bXY[(2 * ty + 10) * 82 + tx + 9].x;
    v2f Xd2; Xd2.x = dXD[(2 * ty + 2) * 72 + tx + 4].x;
             Xd2.y = dXD[(2 * ty + 3) * 72 + tx + 4].x;

    // ---- base pass: 19x19 bilateral guided-filter stats, packed 2 px ----
    // Branchless row masking (ey=0 kills invalid rows; staged halo rows are
    // index-safe zeros) so unroll-2 interleaves two independent row chains.
    v2f sw = bc2(0.f), swx = bc2(0.f), swy = bc2(0.f), swxx = bc2(0.f), swxy = bc2(0.f);
#pragma unroll 2
    for (int k = 0; k < 20; ++k) {
        int nh = h0 - 9 + k;
        bool valid = (unsigned)nh < 512u;            // wave-uniform
        int dy0 = k - 9;                             // -9..10
        const float2* xr = bXY + (2 * ty + k) * 82 + tx;
        v2f rs = bc2(0.f), rsx = bc2(0.f), rsy = bc2(0.f), rsxx = bc2(0.f), rsxy = bc2(0.f);
#pragma unroll
        for (int j = 0; j < 19; ++j) {
            float2 v = xr[j];
            v2f xv = bc2(v.x), yv = bc2(v.y);
            v2f u = xv - Xc2;
            v2f a = vfma(u * k2v, u, bc2(cc[j]));
            v2f w; w.x = fexp2(a.x); w.y = fexp2(a.y);
            rs = rs + w;
            rsx = vfma(w, xv, rsx);
            rsy = vfma(w, yv, rsy);
            v2f tt = w * xv;
            rsxx = vfma(tt, xv, rsxx);
            rsxy = vfma(tt, yv, rsxy);
        }
        v2f ey;
        ey.x = (valid & (dy0 <= 9))  ? sbx[dy0 + 9] : 0.f;
        ey.y = (valid & (dy0 >= -8)) ? sbx[dy0 + 8] : 0.f;
        sw   = vfma(ey, rs,   sw);
        swx  = vfma(ey, rsx,  swx);
        swy  = vfma(ey, rsy,  swy);
        swxx = vfma(ey, rsxx, swxx);
        swxy = vfma(ey, rsxy, swxy);
    }

    // ---- detail pass: 5(h)x9(w) bilateral on residuals, packed 2 px ----
    v2f swd = bc2(0.f), sv = bc2(0.f);
#pragma unroll 2
    for (int kd = 0; kd < 6; ++kd) {
        int nh = h0 - 2 + kd;
        bool valid = (unsigned)nh < 512u;
        int dyd = kd - 2;                            // -2..3
        const float2* dr2 = dXD + (2 * ty + kd) * 72 + tx;
        v2f rs = bc2(0.f), rv = bc2(0.f);
#pragma unroll
        for (int j = 0; j < 9; ++j) {
            float2 v = dr2[j];
            v2f xd = bc2(v.x), dv = bc2(v.y);
            v2f u = xd - Xd2;
            v2f a = vfma(u * k2v, u, bc2(ccd[j]));
            v2f w; w.x = fexp2(a.x); w.y = fexp2(a.y);
            rs = rs + w;
            rv = vfma(w, dv, rv);
        }
        v2f ey;
        ey.x = (valid & (dyd <= 2))  ? sdy[dyd + 2] : 0.f;
        ey.y = (valid & (dyd >= -1)) ? sdy[dyd + 1] : 0.f;
        swd = vfma(ey, rs, swd);
        sv  = vfma(ey, rv, sv);
    }

    // ---- combine & store both pixels ----
    v2f inv; inv.x = 1.0f / sw.x; inv.y = 1.0f / sw.y;
    v2f mx = swx * inv, my = swy * inv;
    v2f varx = vfma(-mx, mx, swxx * inv);
    v2f cov  = vfma(-mx, my, swxy * inv);
    v2f A; A.x = cov.x / (varx.x + 1e-6f); A.y = cov.y / (varx.y + 1e-6f);
    v2f b = my - A * mx;
    v2f bd; bd.x = sv.x / swd.x; bd.y = sv.y / swd.y;
    v2f res = A * Xc2 + b + Xd2 + bd;
    int p0 = h0 * W + c;
    out[p0]     = res.x;
    out[p0 + W] = res.y;
}

extern "C" void kernel_launch(void* const* d_in, const int* in_sizes, int n_in,
                              void* d_out, int out_size, void* d_ws, size_t ws_size,
                              hipStream_t stream) {
    const float* X = (const float*)d_in[0];
    const float* y = (const float*)d_in[1];
    const float* r = (const float*)d_in[2];
    float* out = (float*)d_out;
    float2* partial = (float2*)d_ws;               // 256 float2, fully written each call

    k_minmax<<<256, 256, 0, stream>>>(y, partial);
    k_fused<<<dim3(8, 64), dim3(64, 4), 0, stream>>>(X, y, partial, r, out);
}